// Round 5
// baseline (228.246 us; speedup 1.0000x reference)
//
#include <hip/hip_runtime.h>

typedef __attribute__((ext_vector_type(8))) short bf16x8;
typedef __attribute__((ext_vector_type(4))) float f32x4;

__device__ static inline unsigned short f2bf(float x) {
  unsigned int u = __float_as_uint(x);
  unsigned int r = u + 0x7FFFu + ((u >> 16) & 1u);  // round-to-nearest-even
  return (unsigned short)(r >> 16);
}

// inputs[16384][1000] f32 -> a[16384][1024] bf16 holding 2*inputs (K-pad zeros).
__global__ __launch_bounds__(256) void prep_inputs_k(const float* __restrict__ in,
                                                     unsigned short* __restrict__ a) {
  int idx = blockIdx.x * 256 + threadIdx.x;  // 16384*128
  int row = idx >> 7;
  int g   = idx & 127;
  union { unsigned short u[8]; uint4 v; } pk;
  if (g < 125) {
    const float4* p = (const float4*)(in + (size_t)row * 1000 + g * 8);
    float4 v0 = p[0], v1 = p[1];
    pk.u[0] = f2bf(2.f * v0.x); pk.u[1] = f2bf(2.f * v0.y);
    pk.u[2] = f2bf(2.f * v0.z); pk.u[3] = f2bf(2.f * v0.w);
    pk.u[4] = f2bf(2.f * v1.x); pk.u[5] = f2bf(2.f * v1.y);
    pk.u[6] = f2bf(2.f * v1.z); pk.u[7] = f2bf(2.f * v1.w);
  } else {
    pk.v = make_uint4(0, 0, 0, 0);
  }
  *(uint4*)(a + ((size_t)row << 10) + (g << 3)) = pk.v;
}

// code_book[1000][1000] f32 -> b[1024][1024] bf16 (pads zero) + rowsum[1024] f32
__global__ __launch_bounds__(256) void prep_code_k(const float* __restrict__ cb,
                                                   unsigned short* __restrict__ b,
                                                   float* __restrict__ rowsum) {
  int n = blockIdx.x;  // 1024 blocks
  int t = threadIdx.x;
  float s = 0.f;
#pragma unroll
  for (int j = 0; j < 4; ++j) {
    int c = t + j * 256;
    float v = 0.f;
    if (n < 1000 && c < 1000) v = cb[(size_t)n * 1000 + c];
    s += v;
    b[((size_t)n << 10) + c] = f2bf(v);
  }
  __shared__ float red[256];
  red[t] = s;
  __syncthreads();
  for (int o = 128; o > 0; o >>= 1) {
    if (t < o) red[t] += red[t + o];
    __syncthreads();
  }
  if (t == 0) rowsum[n] = (n < 1000) ? red[0] : 0.f;
}

// Normalize labels to int32, auto-detecting int64 vs int32 device-buffer layout.
__global__ __launch_bounds__(256) void fix_labels_k(const int* __restrict__ raw,
                                                    int* __restrict__ labs) {
  __shared__ int nz;
  int t = threadIdx.x;
  if (t == 0) nz = 0;
  __syncthreads();
  if (raw[2 * t + 1] != 0) atomicAdd(&nz, 1);
  __syncthreads();
  bool is64 = (nz < 32);  // int64 layout -> ~0 nonzero odd slots
  int row = blockIdx.x * 256 + t;
  labs[row] = is64 ? raw[2 * row] : raw[row];
}

// Block = 128 rows x 256 cols, 4 waves (2x2), wave tile 64x128 = 4x8 MFMA
// 16x16x32 bf16, BK=32. Staging is global->VGPR->LDS double-buffer with ONE
// barrier per iter: loads for k+1 issue before the MFMA block (latency hidden
// by compute), vmcnt drains before the ds_writes, and the barrier only waits
// on lgkmcnt (fast LDS). This removes the m97-style vmcnt(0)-at-barrier drain.
// Grid 512 = 128 rt x 4 ct -> 2 blocks/CU; ct=bx&3 keeps each XCD's 512 KB
// B-slice L2-resident. exp(S-40): sigma(S)~10.5, no overflow/underflow.
__global__ __launch_bounds__(256, 2) void coding_loss_k(
    const unsigned short* __restrict__ A,   // [16384][1024] bf16 = 2*inputs
    const unsigned short* __restrict__ B,   // [1024][1024] bf16 = code
    const float* __restrict__ rowsum,       // [1024]
    const int* __restrict__ labels,         // [16384] int32 (normalized)
    float* __restrict__ Z,                  // [4][16384] partial expsums
    float* __restrict__ lin) {              // scalar (pre-zeroed)
  __shared__ __align__(16) unsigned char lds[49152 + 1040];
  unsigned short* buf = (unsigned short*)lds;  // 2 bufs x 12288 elems (B 8192 + A 4096)
  float* zbuf = (float*)(lds + 49152);         // [4][64]
  float* lbuf = zbuf + 256;                    // [4]

  const int t    = threadIdx.x;
  const int lane = t & 63;
  const int w    = t >> 6;
  const int wr   = w >> 1;   // 0..1: rows wr*64..+64
  const int wc   = w & 1;    // 0..1: cols wc*128..+128
  const int g16  = lane >> 4;
  const int c16  = lane & 15;
  const int ct   = blockIdx.x & 3;
  const int rt   = blockIdx.x >> 2;
  const int r0   = rt << 7;
  const int c0   = ct << 8;

  // staging: LDS k-slice sl holds global k-slice sl ^ ((row>>1)&3)
  size_t a_src[2]; int a_dst[2];
#pragma unroll
  for (int i = 0; i < 2; ++i) {
    int ch = i * 256 + t, row = ch >> 2;          // A: 512 chunks (128 rows x 4)
    int sg = (ch & 3) ^ ((row >> 1) & 3);
    a_src[i] = (size_t)(r0 + row) * 1024 + sg * 8;
    a_dst[i] = 8192 + ch * 8;
  }
  size_t b_src[4]; int b_dst[4];
#pragma unroll
  for (int i = 0; i < 4; ++i) {
    int ch = i * 256 + t, row = ch >> 2;          // B: 1024 chunks (256 rows x 4)
    int sg = (ch & 3) ^ ((row >> 1) & 3);
    b_src[i] = (size_t)(c0 + row) * 1024 + sg * 8;
    b_dst[i] = ch * 8;
  }

  // fragment LDS element offsets (within one buffer)
  int a_eoff[4], b_eoff[8];
#pragma unroll
  for (int mi = 0; mi < 4; ++mi) {
    int ar = wr * 64 + mi * 16 + c16;
    a_eoff[mi] = 8192 + ar * 32 + ((g16 ^ ((ar >> 1) & 3)) << 3);
  }
#pragma unroll
  for (int ni = 0; ni < 8; ++ni) {
    int br = wc * 128 + ni * 16 + c16;
    b_eoff[ni] = br * 32 + ((g16 ^ ((br >> 1) & 3)) << 3);
  }

  f32x4 acc[4][8];
#pragma unroll
  for (int mi = 0; mi < 4; ++mi)
#pragma unroll
    for (int ni = 0; ni < 8; ++ni) acc[mi][ni] = (f32x4)(0.f);

  // prologue: stage k=0 through regs into buf 0
  uint4 ra[2], rb[4];
#pragma unroll
  for (int i = 0; i < 2; ++i) ra[i] = *(const uint4*)(A + a_src[i]);
#pragma unroll
  for (int i = 0; i < 4; ++i) rb[i] = *(const uint4*)(B + b_src[i]);
#pragma unroll
  for (int i = 0; i < 2; ++i) *(uint4*)(buf + a_dst[i]) = ra[i];
#pragma unroll
  for (int i = 0; i < 4; ++i) *(uint4*)(buf + b_dst[i]) = rb[i];
  __syncthreads();

  int p = 0;
  for (int k0 = 0; k0 < 1024; k0 += 32) {
    const bool more = (k0 + 32 < 1024);
    if (more) {  // issue k+1 loads early; vmcnt wait lands after the MFMA block
#pragma unroll
      for (int i = 0; i < 2; ++i) ra[i] = *(const uint4*)(A + a_src[i] + k0 + 32);
#pragma unroll
      for (int i = 0; i < 4; ++i) rb[i] = *(const uint4*)(B + b_src[i] + k0 + 32);
    }
    const unsigned short* bp = buf + p * 12288;
    bf16x8 af[4], bf[8];
#pragma unroll
    for (int mi = 0; mi < 4; ++mi) af[mi] = *(const bf16x8*)(bp + a_eoff[mi]);
#pragma unroll
    for (int ni = 0; ni < 8; ++ni) bf[ni] = *(const bf16x8*)(bp + b_eoff[ni]);
#pragma unroll
    for (int mi = 0; mi < 4; ++mi)
#pragma unroll
      for (int ni = 0; ni < 8; ++ni)
        acc[mi][ni] = __builtin_amdgcn_mfma_f32_16x16x32_bf16(af[mi], bf[ni], acc[mi][ni], 0, 0, 0);
    if (more) {
      unsigned short* np = buf + (p ^ 1) * 12288;
#pragma unroll
      for (int i = 0; i < 2; ++i) *(uint4*)(np + a_dst[i]) = ra[i];
#pragma unroll
      for (int i = 0; i < 4; ++i) *(uint4*)(np + b_dst[i]) = rb[i];
    }
    __syncthreads();  // lgkm-only drain: my reads of p done (data dep), writes to p^1 visible
    p ^= 1;
  }

  // ---- epilogue ----
  float rs[8]; int colg[8];
#pragma unroll
  for (int ni = 0; ni < 8; ++ni) {
    colg[ni] = c0 + wc * 128 + ni * 16 + c16;
    rs[ni]   = rowsum[colg[ni]];
  }
  float lacc = 0.f;  // 0.9*S_label + 1e-4*sum_n S
  float ez[4][4];
#pragma unroll
  for (int mi = 0; mi < 4; ++mi)
#pragma unroll
    for (int r = 0; r < 4; ++r) {
      int labv = labels[r0 + wr * 64 + mi * 16 + g16 * 4 + r];
      float e = 0.f;
#pragma unroll
      for (int ni = 0; ni < 8; ++ni) {
        float S = acc[mi][ni][r] - rs[ni];  // padded cols (>=1000): S==0, harmless
        e += __expf(S - 40.f);
        lacc += 1e-4f * S;
        if (colg[ni] == labv) lacc += 0.9f * S;
      }
      ez[mi][r] = e;
    }
#pragma unroll
  for (int d = 1; d < 16; d <<= 1)
#pragma unroll
    for (int mi = 0; mi < 4; ++mi)
#pragma unroll
      for (int r = 0; r < 4; ++r) ez[mi][r] += __shfl_xor(ez[mi][r], d, 64);
  if (c16 == 0) {
#pragma unroll
    for (int mi = 0; mi < 4; ++mi)
#pragma unroll
      for (int r = 0; r < 4; ++r) zbuf[w * 64 + mi * 16 + g16 * 4 + r] = ez[mi][r];
  }
#pragma unroll
  for (int d = 1; d < 64; d <<= 1) lacc += __shfl_xor(lacc, d, 64);
  if (lane == 0) lbuf[w] = lacc;
  __syncthreads();
  if (t < 128) {  // tile row t: sum the two wc waves of its row half
    int wrg = t >> 6, lr = t & 63;
    float z = zbuf[(wrg * 2 + 0) * 64 + lr] + zbuf[(wrg * 2 + 1) * 64 + lr];
    Z[ct * 16384 + r0 + t] = z;  // single writer per slot
  }
  if (t == 0) atomicAdd(lin, lbuf[0] + lbuf[1] + lbuf[2] + lbuf[3]);
}

// out = mean_r(40 + log(sum_ct Z[ct][r])) - lin/16384
__global__ __launch_bounds__(256) void finalize_k(const float* __restrict__ Z,
                                                  const float* __restrict__ lin,
                                                  float* __restrict__ out) {
  int t = threadIdx.x;
  int row = blockIdx.x * 256 + t;
  float v = 40.f + logf(Z[row] + Z[16384 + row] + Z[2 * 16384 + row] + Z[3 * 16384 + row]);
#pragma unroll
  for (int d = 1; d < 64; d <<= 1) v += __shfl_xor(v, d, 64);
  __shared__ float s[4];
  if ((t & 63) == 0) s[t >> 6] = v;
  __syncthreads();
  if (t == 0) {
    float tot = s[0] + s[1] + s[2] + s[3];
    if (blockIdx.x == 0) tot -= lin[0];
    atomicAdd(out, tot * (1.f / 16384.f));
  }
}

extern "C" void kernel_launch(void* const* d_in, const int* in_sizes, int n_in,
                              void* d_out, int out_size, void* d_ws, size_t ws_size,
                              hipStream_t stream) {
  const float* inputs = (const float*)d_in[0];
  const int* labraw   = (const int*)d_in[1];
  const float* code   = (const float*)d_in[2];

  unsigned short* a_bf = (unsigned short*)d_ws;                 // 32 MB
  unsigned short* b_bf = a_bf + (size_t)16384 * 1024;           // 2 MB
  float* rowsum        = (float*)(b_bf + (size_t)1024 * 1024);  // 4 KB
  float* Z             = rowsum + 1024;                         // [4][16384] = 256 KB
  float* lin           = Z + 4 * 16384;                         // 4 B
  int* labs            = (int*)(lin + 1);                       // 64 KB

  hipMemsetAsync(lin, 0, sizeof(float), stream);
  hipMemsetAsync(d_out, 0, sizeof(float), stream);
  fix_labels_k<<<64, 256, 0, stream>>>(labraw, labs);
  prep_inputs_k<<<8192, 256, 0, stream>>>(inputs, a_bf);
  prep_code_k<<<1024, 256, 0, stream>>>(code, b_bf, rowsum);
  coding_loss_k<<<512, 256, 0, stream>>>(a_bf, b_bf, rowsum, labs, Z, lin);
  finalize_k<<<64, 256, 0, stream>>>(Z, lin, (float*)d_out);
}

// Round 7
// 148.482 us; speedup vs baseline: 1.5372x; 1.5372x over previous
//
#include <hip/hip_runtime.h>

typedef __attribute__((ext_vector_type(8))) short bf16x8;
typedef __attribute__((ext_vector_type(4))) float f32x4;

#define AS1 __attribute__((address_space(1)))
#define AS3 __attribute__((address_space(3)))

__device__ static inline void gl2lds16(const void* g, void* l) {
  // async global->LDS, 16B per lane; HW writes wave-uniform base + lane*16
  __builtin_amdgcn_global_load_lds((const AS1 unsigned int*)g, (AS3 unsigned int*)l, 16, 0, 0);
}

__device__ static inline unsigned short f2bf(float x) {
  unsigned int u = __float_as_uint(x);
  unsigned int r = u + 0x7FFFu + ((u >> 16) & 1u);  // round-to-nearest-even
  return (unsigned short)(r >> 16);
}

// inputs[16384][1000] f32 -> a[16384][1024] bf16 holding 2*inputs (K-pad zeros).
__global__ __launch_bounds__(256) void prep_inputs_k(const float* __restrict__ in,
                                                     unsigned short* __restrict__ a) {
  int idx = blockIdx.x * 256 + threadIdx.x;  // 16384*128
  int row = idx >> 7;
  int g   = idx & 127;
  union { unsigned short u[8]; uint4 v; } pk;
  if (g < 125) {
    const float4* p = (const float4*)(in + (size_t)row * 1000 + g * 8);
    float4 v0 = p[0], v1 = p[1];
    pk.u[0] = f2bf(2.f * v0.x); pk.u[1] = f2bf(2.f * v0.y);
    pk.u[2] = f2bf(2.f * v0.z); pk.u[3] = f2bf(2.f * v0.w);
    pk.u[4] = f2bf(2.f * v1.x); pk.u[5] = f2bf(2.f * v1.y);
    pk.u[6] = f2bf(2.f * v1.z); pk.u[7] = f2bf(2.f * v1.w);
  } else {
    pk.v = make_uint4(0, 0, 0, 0);
  }
  *(uint4*)(a + ((size_t)row << 10) + (g << 3)) = pk.v;
}

// code_book[1000][1000] f32 -> b[1024][1024] bf16 (pads zero) + rowsum[1024] f32
__global__ __launch_bounds__(256) void prep_code_k(const float* __restrict__ cb,
                                                   unsigned short* __restrict__ b,
                                                   float* __restrict__ rowsum) {
  int n = blockIdx.x;  // 1024 blocks
  int t = threadIdx.x;
  float s = 0.f;
#pragma unroll
  for (int j = 0; j < 4; ++j) {
    int c = t + j * 256;
    float v = 0.f;
    if (n < 1000 && c < 1000) v = cb[(size_t)n * 1000 + c];
    s += v;
    b[((size_t)n << 10) + c] = f2bf(v);
  }
  __shared__ float red[256];
  red[t] = s;
  __syncthreads();
  for (int o = 128; o > 0; o >>= 1) {
    if (t < o) red[t] += red[t + o];
    __syncthreads();
  }
  if (t == 0) rowsum[n] = (n < 1000) ? red[0] : 0.f;
}

// Normalize labels to int32, auto-detecting int64 vs int32 device-buffer layout.
__global__ __launch_bounds__(256) void fix_labels_k(const int* __restrict__ raw,
                                                    int* __restrict__ labs) {
  __shared__ int nz;
  int t = threadIdx.x;
  if (t == 0) nz = 0;
  __syncthreads();
  if (raw[2 * t + 1] != 0) atomicAdd(&nz, 1);
  __syncthreads();
  bool is64 = (nz < 32);  // int64 layout -> ~0 nonzero odd slots
  int row = blockIdx.x * 256 + t;
  labs[row] = is64 ? raw[2 * row] : raw[row];
}

// Block 128x256, 4 waves (2x2), wave 64x128 = 4x8 MFMA 16x16x32 bf16, BK=32.
// K-loop: wait-then-barrier pipeline (CK/AITER LDS ping-pong discipline).
// Per iter k: STAGE B(k+1),A(k+2) -> s_waitcnt vmcnt(8) [completes OWN tile-k
// loads] -> s_barrier [all waves' tile-k loads done => LDS coherent] ->
// COMPUTE(k) -> s_barrier [compute-k reads issued before anyone overwrites].
// R6's NaN was barrier-before-wait: vmcnt is per-wave, so other waves' DMA
// wasn't guaranteed complete at read time. A triple-buffered (dist 2, HBM
// ~900cyc budget), B double-buffered (dist 1, L2 ~200cyc budget).
// Grid 512 = 128rt x 4ct; exp(S-40): sigma(S)~10.5, no overflow/underflow.
__global__ __launch_bounds__(256, 2) void coding_loss_k(
    const unsigned short* __restrict__ A,   // [16384][1024] bf16 = 2*inputs
    const unsigned short* __restrict__ B,   // [1024][1024] bf16 = code
    const float* __restrict__ rowsum,       // [1024]
    const int* __restrict__ labels,         // [16384] int32 (normalized)
    float* __restrict__ Z,                  // [4][16384] partial expsums
    float* __restrict__ lin) {              // scalar (pre-zeroed)
  // A bufs: 3 x 4096 elems (8KB each); B bufs: 2 x 8192 elems (16KB each); + epi
  __shared__ __align__(16) unsigned char lds[24576 + 32768 + 1040];
  unsigned short* Ab0 = (unsigned short*)lds;
  unsigned short* Ab1 = Ab0 + 4096;
  unsigned short* Ab2 = Ab1 + 4096;
  unsigned short* Bb0 = Ab2 + 4096;
  unsigned short* Bb1 = Bb0 + 8192;
  float* zbuf = (float*)(lds + 57344);  // [4][64]
  float* lbuf = zbuf + 256;             // [4]

  const int t    = threadIdx.x;
  const int lane = t & 63;
  const int w    = t >> 6;
  const int wr   = w >> 1;   // 0..1: rows wr*64..+64
  const int wc   = w & 1;    // 0..1: cols wc*128..+128
  const int g16  = lane >> 4;
  const int c16  = lane & 15;
  const int ct   = blockIdx.x & 3;
  const int rt   = blockIdx.x >> 2;
  const int r0   = rt << 7;
  const int c0   = ct << 8;

  // staging: LDS k-slice sl holds global k-slice sl ^ ((row>>1)&3)
  size_t a_src[2]; int a_dst[2];
#pragma unroll
  for (int i = 0; i < 2; ++i) {
    int ch = i * 256 + t, row = ch >> 2;          // A: 512 chunks (128 rows x 4)
    int sg = (ch & 3) ^ ((row >> 1) & 3);
    a_src[i] = (size_t)(r0 + row) * 1024 + sg * 8;
    a_dst[i] = ch * 8;
  }
  size_t b_src[4]; int b_dst[4];
#pragma unroll
  for (int i = 0; i < 4; ++i) {
    int ch = i * 256 + t, row = ch >> 2;          // B: 1024 chunks (256 rows x 4)
    int sg = (ch & 3) ^ ((row >> 1) & 3);
    b_src[i] = (size_t)(c0 + row) * 1024 + sg * 8;
    b_dst[i] = ch * 8;
  }

  // fragment LDS element offsets (within one buffer)
  int a_eoff[4], b_eoff[8];
#pragma unroll
  for (int mi = 0; mi < 4; ++mi) {
    int ar = wr * 64 + mi * 16 + c16;
    a_eoff[mi] = ar * 32 + ((g16 ^ ((ar >> 1) & 3)) << 3);
  }
#pragma unroll
  for (int ni = 0; ni < 8; ++ni) {
    int br = wc * 128 + ni * 16 + c16;
    b_eoff[ni] = br * 32 + ((g16 ^ ((br >> 1) & 3)) << 3);
  }

  f32x4 acc[4][8];
#pragma unroll
  for (int mi = 0; mi < 4; ++mi)
#pragma unroll
    for (int ni = 0; ni < 8; ++ni) acc[mi][ni] = (f32x4)(0.f);

#define STAGE_A(kk, dst) \
  { _Pragma("unroll") for (int i = 0; i < 2; ++i) gl2lds16(A + a_src[i] + (kk) * 32, (dst) + a_dst[i]); }
#define STAGE_B(kk, dst) \
  { _Pragma("unroll") for (int i = 0; i < 4; ++i) gl2lds16(B + b_src[i] + (kk) * 32, (dst) + b_dst[i]); }
#define COMPUTE(pa, pb)                                                                   \
  {                                                                                       \
    bf16x8 af[4], bf[8];                                                                  \
    _Pragma("unroll") for (int mi = 0; mi < 4; ++mi) af[mi] = *(const bf16x8*)((pa) + a_eoff[mi]); \
    _Pragma("unroll") for (int ni = 0; ni < 8; ++ni) bf[ni] = *(const bf16x8*)((pb) + b_eoff[ni]); \
    _Pragma("unroll") for (int mi = 0; mi < 4; ++mi)                                      \
      _Pragma("unroll") for (int ni = 0; ni < 8; ++ni)                                    \
        acc[mi][ni] = __builtin_amdgcn_mfma_f32_16x16x32_bf16(af[mi], bf[ni], acc[mi][ni], 0, 0, 0); \
  }
  // s_waitcnt imm: lgkm=0xF (bits 11:8), exp=7 (6:4), vmcnt low (3:0), vmcnt hi (15:14)
#define WAITVM(n) __builtin_amdgcn_s_waitcnt(0xF70 | (n))

  // prologue FIFO: [A0 x2, B0 x4, A1 x2] = 8 outstanding
  STAGE_A(0, Ab0);
  STAGE_B(0, Bb0);
  STAGE_A(1, Ab1);

  unsigned short *pa_cur = Ab0, *pa_nxt = Ab1, *pa_stg = Ab2;
  unsigned short *pb_cur = Bb0, *pb_stg = Bb1;

  // steady: kc = 0..29. Entry FIFO: [A(kc)2, B(kc)4, A(kc+1)2] = 8.
#pragma unroll 2
  for (int kc = 0; kc < 30; ++kc) {
    STAGE_B(kc + 1, pb_stg);   // into tile (kc-1)'s buffer: readers done (end barrier kc-1)
    STAGE_A(kc + 2, pa_stg);   // into tile (kc-1)'s A buffer: same
    WAITVM(8);                 // own A(kc)+B(kc) landed (14 outstanding -> 8)
    __builtin_amdgcn_s_barrier();  // all waves' tile-kc loads landed
    COMPUTE(pa_cur, pb_cur);
    __builtin_amdgcn_s_barrier();  // all compute-kc LDS reads issued
    unsigned short* tmp = pa_cur; pa_cur = pa_nxt; pa_nxt = pa_stg; pa_stg = tmp;
    tmp = pb_cur; pb_cur = pb_stg; pb_stg = tmp;
  }
  // kc = 30: entry [A30 x2, B30 x4, A31 x2]; stage B31 -> 12; wait 6 = A30+B30 done
  {
    STAGE_B(31, pb_stg);
    WAITVM(6);
    __builtin_amdgcn_s_barrier();
    COMPUTE(pa_cur, pb_cur);
    __builtin_amdgcn_s_barrier();
    unsigned short* tmp = pa_cur; pa_cur = pa_nxt; pa_nxt = tmp;
    tmp = pb_cur; pb_cur = pb_stg; pb_stg = tmp;
  }
  // kc = 31: entry [A31 x2, B31 x4]
  {
    WAITVM(0);
    __builtin_amdgcn_s_barrier();
    COMPUTE(pa_cur, pb_cur);
  }

  // ---- epilogue ----
  float rs[8]; int colg[8];
#pragma unroll
  for (int ni = 0; ni < 8; ++ni) {
    colg[ni] = c0 + wc * 128 + ni * 16 + c16;
    rs[ni]   = rowsum[colg[ni]];
  }
  float lacc = 0.f;  // 0.9*S_label + 1e-4*sum_n S
  float ez[4][4];
#pragma unroll
  for (int mi = 0; mi < 4; ++mi)
#pragma unroll
    for (int r = 0; r < 4; ++r) {
      int labv = labels[r0 + wr * 64 + mi * 16 + g16 * 4 + r];
      float e = 0.f;
#pragma unroll
      for (int ni = 0; ni < 8; ++ni) {
        float S = acc[mi][ni][r] - rs[ni];  // padded cols (>=1000): S==0, harmless
        e += __expf(S - 40.f);
        lacc += 1e-4f * S;
        if (colg[ni] == labv) lacc += 0.9f * S;
      }
      ez[mi][r] = e;
    }
#pragma unroll
  for (int d = 1; d < 16; d <<= 1)
#pragma unroll
    for (int mi = 0; mi < 4; ++mi)
#pragma unroll
      for (int r = 0; r < 4; ++r) ez[mi][r] += __shfl_xor(ez[mi][r], d, 64);
  if (c16 == 0) {
#pragma unroll
    for (int mi = 0; mi < 4; ++mi)
#pragma unroll
      for (int r = 0; r < 4; ++r) zbuf[w * 64 + mi * 16 + g16 * 4 + r] = ez[mi][r];
  }
#pragma unroll
  for (int d = 1; d < 64; d <<= 1) lacc += __shfl_xor(lacc, d, 64);
  if (lane == 0) lbuf[w] = lacc;
  __syncthreads();
  if (t < 128) {  // tile row t: sum the two wc waves of its row half
    int wrg = t >> 6, lr = t & 63;
    float z = zbuf[(wrg * 2 + 0) * 64 + lr] + zbuf[(wrg * 2 + 1) * 64 + lr];
    Z[ct * 16384 + r0 + t] = z;  // single writer per slot
  }
  if (t == 0) atomicAdd(lin, lbuf[0] + lbuf[1] + lbuf[2] + lbuf[3]);
#undef STAGE_A
#undef STAGE_B
#undef COMPUTE
#undef WAITVM
}

// out = mean_r(40 + log(sum_ct Z[ct][r])) - lin/16384
__global__ __launch_bounds__(256) void finalize_k(const float* __restrict__ Z,
                                                  const float* __restrict__ lin,
                                                  float* __restrict__ out) {
  int t = threadIdx.x;
  int row = blockIdx.x * 256 + t;
  float v = 40.f + logf(Z[row] + Z[16384 + row] + Z[2 * 16384 + row] + Z[3 * 16384 + row]);
#pragma unroll
  for (int d = 1; d < 64; d <<= 1) v += __shfl_xor(v, d, 64);
  __shared__ float s[4];
  if ((t & 63) == 0) s[t >> 6] = v;
  __syncthreads();
  if (t == 0) {
    float tot = s[0] + s[1] + s[2] + s[3];
    if (blockIdx.x == 0) tot -= lin[0];
    atomicAdd(out, tot * (1.f / 16384.f));
  }
}

extern "C" void kernel_launch(void* const* d_in, const int* in_sizes, int n_in,
                              void* d_out, int out_size, void* d_ws, size_t ws_size,
                              hipStream_t stream) {
  const float* inputs = (const float*)d_in[0];
  const int* labraw   = (const int*)d_in[1];
  const float* code   = (const float*)d_in[2];

  unsigned short* a_bf = (unsigned short*)d_ws;                 // 32 MB
  unsigned short* b_bf = a_bf + (size_t)16384 * 1024;           // 2 MB
  float* rowsum        = (float*)(b_bf + (size_t)1024 * 1024);  // 4 KB
  float* Z             = rowsum + 1024;                         // [4][16384] = 256 KB
  float* lin           = Z + 4 * 16384;                         // 4 B
  int* labs            = (int*)(lin + 1);                       // 64 KB

  hipMemsetAsync(lin, 0, sizeof(float), stream);
  hipMemsetAsync(d_out, 0, sizeof(float), stream);
  fix_labels_k<<<64, 256, 0, stream>>>(labraw, labs);
  prep_inputs_k<<<8192, 256, 0, stream>>>(inputs, a_bf);
  prep_code_k<<<1024, 256, 0, stream>>>(code, b_bf, rowsum);
  coding_loss_k<<<512, 256, 0, stream>>>(a_bf, b_bf, rowsum, labs, Z, lin);
  finalize_k<<<64, 256, 0, stream>>>(Z, lin, (float*)d_out);
}

// Round 8
// 145.441 us; speedup vs baseline: 1.5693x; 1.0209x over previous
//
#include <hip/hip_runtime.h>

typedef __attribute__((ext_vector_type(8))) short bf16x8;
typedef __attribute__((ext_vector_type(4))) float f32x4;

#define AS1 __attribute__((address_space(1)))
#define AS3 __attribute__((address_space(3)))

__device__ static inline void gl2lds16(const void* g, void* l) {
  // async global->LDS, 16B per lane; HW writes wave-uniform base + lane*16
  __builtin_amdgcn_global_load_lds((const AS1 unsigned int*)g, (AS3 unsigned int*)l, 16, 0, 0);
}

__device__ static inline unsigned short f2bf(float x) {
  unsigned int u = __float_as_uint(x);
  unsigned int r = u + 0x7FFFu + ((u >> 16) & 1u);  // round-to-nearest-even
  return (unsigned short)(r >> 16);
}

// Fused prep (single graph node):
//  bx < 8192   : inputs[16384][1000] f32 -> a[16384][1024] bf16 = 2*inputs (pad 0)
//  bx < 9216   : code_book row cast -> b[1024][1024] bf16 + rowsum[1024]
//  bx >= 9216  : labels normalize (int64-vs-int32 autodetect); bx==9216,t==0 zeroes lin/out
__global__ __launch_bounds__(256) void prep_all_k(
    const float* __restrict__ in, const int* __restrict__ labraw,
    const float* __restrict__ cb, unsigned short* __restrict__ a,
    unsigned short* __restrict__ b, float* __restrict__ rowsum,
    int* __restrict__ labs, float* __restrict__ lin, float* __restrict__ out) {
  const int bx = blockIdx.x, t = threadIdx.x;
  if (bx < 8192) {
    int idx = bx * 256 + t;  // 16384 rows x 128 groups
    int row = idx >> 7, g = idx & 127;
    union { unsigned short u[8]; uint4 v; } pk;
    if (g < 125) {
      const float4* p = (const float4*)(in + (size_t)row * 1000 + g * 8);
      float4 v0 = p[0], v1 = p[1];
      pk.u[0] = f2bf(2.f * v0.x); pk.u[1] = f2bf(2.f * v0.y);
      pk.u[2] = f2bf(2.f * v0.z); pk.u[3] = f2bf(2.f * v0.w);
      pk.u[4] = f2bf(2.f * v1.x); pk.u[5] = f2bf(2.f * v1.y);
      pk.u[6] = f2bf(2.f * v1.z); pk.u[7] = f2bf(2.f * v1.w);
    } else {
      pk.v = make_uint4(0, 0, 0, 0);
    }
    *(uint4*)(a + ((size_t)row << 10) + (g << 3)) = pk.v;
  } else if (bx < 9216) {
    int n = bx - 8192;
    float s = 0.f;
#pragma unroll
    for (int j = 0; j < 4; ++j) {
      int c = t + j * 256;
      float v = 0.f;
      if (n < 1000 && c < 1000) v = cb[(size_t)n * 1000 + c];
      s += v;
      b[((size_t)n << 10) + c] = f2bf(v);
    }
    __shared__ float red[256];
    red[t] = s;
    __syncthreads();
    for (int o = 128; o > 0; o >>= 1) {
      if (t < o) red[t] += red[t + o];
      __syncthreads();
    }
    if (t == 0) rowsum[n] = (n < 1000) ? red[0] : 0.f;
  } else {
    __shared__ int nz;
    if (t == 0) nz = 0;
    __syncthreads();
    if (labraw[2 * t + 1] != 0) atomicAdd(&nz, 1);
    __syncthreads();
    bool is64 = (nz < 32);
    int row = (bx - 9216) * 256 + t;
    labs[row] = is64 ? labraw[2 * row] : labraw[row];
    if (bx == 9216 && t == 0) { lin[0] = 0.f; out[0] = 0.f; }
  }
}

// Block 256x256, 4 waves (2x2), WAVE TILE 128x128 = 8x8 MFMA 16x16x32 bf16
// (acc 256 regs/lane, unified VGPR file, 1 wave/SIMD). BK=32, A/B LDS
// double-buffered = 64 KB exactly; R7-proven wait(vmcnt)-then-barrier K-loop.
// Rationale: R4/R7 plateaued at ~29% MfmaUtil because LDS-read bytes/FLOP
// (3/N+3/M = 0.035) x 13.5 kFLOP/cyc demanded ~475 B/cyc of LDS vs ~112-256
// available. 128x128 wave tiles cut it to 0.023 (2/256+... read amp: af+bf =
// 16 KB/CU/iter vs MFMA 310 cyc -> ceiling ~55-75%).
// Grid 256 = 64 rt x 4 ct = 1 block/CU; ct pins each XCD's 512KB B-slice in L2.
// exp(S-40): sigma(S)~10.5, no overflow/underflow. Epilogue aliases LDS.
__global__ __launch_bounds__(256, 1) void coding_loss_k(
    const unsigned short* __restrict__ A,   // [16384][1024] bf16 = 2*inputs
    const unsigned short* __restrict__ B,   // [1024][1024] bf16 = code
    const float* __restrict__ rowsum,       // [1024]
    const int* __restrict__ labels,         // [16384] int32 (normalized)
    float* __restrict__ Z,                  // [4][16384] partial expsums
    float* __restrict__ lin) {              // scalar (zeroed by prep)
  __shared__ __align__(16) unsigned short lds[32768];  // 64 KB
  unsigned short* Ab0 = lds;           // 8192 elems (256 rows x 32)
  unsigned short* Ab1 = lds + 8192;
  unsigned short* Bb0 = lds + 16384;
  unsigned short* Bb1 = lds + 24576;

  const int t    = threadIdx.x;
  const int lane = t & 63;
  const int w    = t >> 6;
  const int wr   = w >> 1;   // 0..1: rows wr*128..+128
  const int wc   = w & 1;    // 0..1: cols wc*128..+128
  const int g16  = lane >> 4;
  const int c16  = lane & 15;
  const int ct   = blockIdx.x & 3;
  const int rt   = blockIdx.x >> 2;
  const int r0   = rt << 8;
  const int c0   = ct << 8;

  // staging: 256-row x 32-k tiles, 1024 16B-chunks; LDS k-slice sl holds
  // global slice sl ^ ((row>>1)&3) (R7-verified conflict-free both sides)
  size_t a_src[4], b_src[4]; int dstoff[4];
#pragma unroll
  for (int i = 0; i < 4; ++i) {
    int ch = i * 256 + t, row = ch >> 2;
    int sg = (ch & 3) ^ ((row >> 1) & 3);
    a_src[i] = (size_t)(r0 + row) * 1024 + sg * 8;
    b_src[i] = (size_t)(c0 + row) * 1024 + sg * 8;
    dstoff[i] = ch * 8;
  }
  // fragment LDS element offsets (within one buffer)
  int a_eoff[8], b_eoff[8];
#pragma unroll
  for (int i = 0; i < 8; ++i) {
    int ar = wr * 128 + i * 16 + c16;
    a_eoff[i] = ar * 32 + ((g16 ^ ((ar >> 1) & 3)) << 3);
    int br = wc * 128 + i * 16 + c16;
    b_eoff[i] = br * 32 + ((g16 ^ ((br >> 1) & 3)) << 3);
  }

  f32x4 acc[8][8];
#pragma unroll
  for (int mi = 0; mi < 8; ++mi)
#pragma unroll
    for (int ni = 0; ni < 8; ++ni) acc[mi][ni] = (f32x4)(0.f);

#define STAGE_A(kk, dst) \
  { _Pragma("unroll") for (int i = 0; i < 4; ++i) gl2lds16(A + a_src[i] + (kk) * 32, (dst) + dstoff[i]); }
#define STAGE_B(kk, dst) \
  { _Pragma("unroll") for (int i = 0; i < 4; ++i) gl2lds16(B + b_src[i] + (kk) * 32, (dst) + dstoff[i]); }
#define COMPUTE(pa, pb)                                                                   \
  {                                                                                       \
    bf16x8 af[8], bf[8];                                                                  \
    _Pragma("unroll") for (int i = 0; i < 8; ++i) af[i] = *(const bf16x8*)((pa) + a_eoff[i]); \
    _Pragma("unroll") for (int i = 0; i < 8; ++i) bf[i] = *(const bf16x8*)((pb) + b_eoff[i]); \
    _Pragma("unroll") for (int mi = 0; mi < 8; ++mi)                                      \
      _Pragma("unroll") for (int ni = 0; ni < 8; ++ni)                                    \
        acc[mi][ni] = __builtin_amdgcn_mfma_f32_16x16x32_bf16(af[mi], bf[ni], acc[mi][ni], 0, 0, 0); \
  }

  // prologue: tile 0 -> buf 0 (8 DMA outstanding)
  STAGE_A(0, Ab0);
  STAGE_B(0, Bb0);
  unsigned short *pa = Ab0, *pan = Ab1, *pb = Bb0, *pbn = Bb1;

  // steady: entry FIFO [A(J)4 B(J)4]; issue A(J+1),B(J+1) -> 16; vmcnt(8)
  // completes own tile-J loads; barrier makes them block-visible (R7 rule).
#pragma unroll 2
  for (int J = 0; J < 31; ++J) {
    STAGE_A(J + 1, pan);
    STAGE_B(J + 1, pbn);
    __builtin_amdgcn_s_waitcnt(0xF78);  // vmcnt(8), lgkm/exp free
    __builtin_amdgcn_s_barrier();
    COMPUTE(pa, pb);
    __builtin_amdgcn_s_barrier();       // readers done before next overwrite
    unsigned short* x = pa; pa = pan; pan = x;
    x = pb; pb = pbn; pbn = x;
  }
  __builtin_amdgcn_s_waitcnt(0xF70);    // vmcnt(0)
  __builtin_amdgcn_s_barrier();
  COMPUTE(pa, pb);
  __syncthreads();  // drain before aliasing LDS for epilogue

  // ---- epilogue (zbuf aliases the staging LDS) ----
  float* zbuf = (float*)lds;   // [4 waves][128 rows]
  float* lbuf = zbuf + 512;    // [4]
  float rs[8]; int gcol[8];
#pragma unroll
  for (int ni = 0; ni < 8; ++ni) {
    gcol[ni] = c0 + wc * 128 + ni * 16 + c16;
    rs[ni]   = rowsum[gcol[ni]];
  }
  float lacc = 0.f;  // 0.9*S_label + 1e-4*sum S
#pragma unroll
  for (int mi = 0; mi < 8; ++mi) {
#pragma unroll
    for (int r = 0; r < 4; ++r) {
      int lrow = mi * 16 + g16 * 4 + r;
      int labv = labels[r0 + wr * 128 + lrow];
      float e = 0.f;
#pragma unroll
      for (int ni = 0; ni < 8; ++ni) {
        float S = acc[mi][ni][r] - rs[ni];  // padded cols: S==0, harmless
        e += __expf(S - 40.f);
        lacc += 1e-4f * S;
        if (gcol[ni] == labv) lacc += 0.9f * S;
      }
      e += __shfl_xor(e, 1, 64);
      e += __shfl_xor(e, 2, 64);
      e += __shfl_xor(e, 4, 64);
      e += __shfl_xor(e, 8, 64);
      if (c16 == 0) zbuf[w * 128 + lrow] = e;
    }
  }
#pragma unroll
  for (int d = 1; d < 64; d <<= 1) lacc += __shfl_xor(lacc, d, 64);
  if (lane == 0) lbuf[w] = lacc;
  __syncthreads();
  {  // row t of the 256-row block: sum wc=0,1 wave halves
    int wrg = t >> 7, l7 = t & 127;
    float z = zbuf[(wrg * 2 + 0) * 128 + l7] + zbuf[(wrg * 2 + 1) * 128 + l7];
    Z[ct * 16384 + r0 + t] = z;  // single writer per slot
  }
  if (t == 0) atomicAdd(lin, lbuf[0] + lbuf[1] + lbuf[2] + lbuf[3]);
#undef STAGE_A
#undef STAGE_B
#undef COMPUTE
}

// out = mean_r(40 + log(sum_ct Z[ct][r])) - lin/16384
__global__ __launch_bounds__(256) void finalize_k(const float* __restrict__ Z,
                                                  const float* __restrict__ lin,
                                                  float* __restrict__ out) {
  int t = threadIdx.x;
  int row = blockIdx.x * 256 + t;
  float v = 40.f + logf(Z[row] + Z[16384 + row] + Z[2 * 16384 + row] + Z[3 * 16384 + row]);
#pragma unroll
  for (int d = 1; d < 64; d <<= 1) v += __shfl_xor(v, d, 64);
  __shared__ float s[4];
  if ((t & 63) == 0) s[t >> 6] = v;
  __syncthreads();
  if (t == 0) {
    float tot = s[0] + s[1] + s[2] + s[3];
    if (blockIdx.x == 0) tot -= lin[0];
    atomicAdd(out, tot * (1.f / 16384.f));
  }
}

extern "C" void kernel_launch(void* const* d_in, const int* in_sizes, int n_in,
                              void* d_out, int out_size, void* d_ws, size_t ws_size,
                              hipStream_t stream) {
  const float* inputs = (const float*)d_in[0];
  const int* labraw   = (const int*)d_in[1];
  const float* code   = (const float*)d_in[2];

  unsigned short* a_bf = (unsigned short*)d_ws;                 // 32 MB
  unsigned short* b_bf = a_bf + (size_t)16384 * 1024;           // 2 MB
  float* rowsum        = (float*)(b_bf + (size_t)1024 * 1024);  // 4 KB
  float* Z             = rowsum + 1024;                         // [4][16384] = 256 KB
  float* lin           = Z + 4 * 16384;                         // 4 B
  int* labs            = (int*)(lin + 1);                       // 64 KB

  // 3 graph nodes total (launch overhead was ~half of R7's wall time)
  prep_all_k<<<9280, 256, 0, stream>>>(inputs, labraw, code, a_bf, b_bf, rowsum,
                                       labs, lin, (float*)d_out);
  coding_loss_k<<<256, 256, 0, stream>>>(a_bf, b_bf, rowsum, labs, Z, lin);
  finalize_k<<<64, 256, 0, stream>>>(Z, lin, (float*)d_out);
}